// Round 11
// baseline (56.366 us; speedup 1.0000x reference)
//
#include <hip/hip_runtime.h>

#define H 1024
#define W 1024
#define OH 1016
#define OW 1016
#define NB 16
#define BAND 16            // output rows per wave
#define STEPS (BAND + 8)   // input rows swept per wave
#define NBANDS 64          // 64*16 = 1024 >= 1016
#define NGRP 3             // column groups, bases {0, 504, 1008}
#define WPB 4              // waves per block

typedef float vfloat4 __attribute__((ext_vector_type(4)));

__device__ __forceinline__ void racc(float4& acc, const float4& nw, const float4& old) {
    acc.x += nw.x - old.x; acc.y += nw.y - old.y;
    acc.z += nw.z - old.z; acc.w += nw.w - old.w;
}

__global__ __launch_bounds__(256, 1)
void cov_kernel(const float* __restrict__ xg,
                const float* __restrict__ yg,
                float* __restrict__ outg) {
    const int t    = threadIdx.x & 63;
    const int wv   = threadIdx.x >> 6;
    const int grp  = blockIdx.x;                   // 0,1,2
    const int band = blockIdx.y * WPB + wv;
    const int img  = blockIdx.z;

    const int gbase = grp * 504;
    const int cb = gbase + 8 * t;                  // lane's first column (8 cols/lane)
    const int O  = band * BAND;
    const bool lok = (cb <= W - 8);                // both chunks in range
    const bool sok = (t <= 62) && (cb <= 1008);    // exact, gap/dup-free coverage

    const float* xb = xg + (size_t)img * H * W;
    const float* yb = yg + (size_t)img * H * W;
    float* ob = outg + (size_t)img * OH * OW;

    const float4 z4 = make_float4(0.f, 0.f, 0.f, 0.f);
    float4 hxA[5], hxB[5], hyA[5], hyB[5], hpA[5], hpB[5];
    #pragma unroll
    for (int i = 0; i < 5; ++i) {
        hxA[i] = z4; hxB[i] = z4; hyA[i] = z4; hyB[i] = z4; hpA[i] = z4; hpB[i] = z4;
    }
    float4 csxA = z4, csxB = z4, csyA = z4, csyB = z4, psA = z4, psB = z4;
    const float k = 1.0f / 25.0f;

    // depth-2 prefetch pending buffers (statically indexed after full unroll)
    float4 pxA[2], pxB[2], pyA[2], pyB[2];
    #pragma unroll
    for (int i = 0; i < 2; ++i) {
        const int r = O + i;
        float4 a = z4, b2 = z4, c = z4, d = z4;
        if (lok && r < H) {
            a  = *reinterpret_cast<const float4*>(xb + (size_t)r * W + cb);
            b2 = *reinterpret_cast<const float4*>(xb + (size_t)r * W + cb + 4);
            c  = *reinterpret_cast<const float4*>(yb + (size_t)r * W + cb);
            d  = *reinterpret_cast<const float4*>(yb + (size_t)r * W + cb + 4);
        }
        pxA[i] = a; pxB[i] = b2; pyA[i] = c; pyB[i] = d;
    }

    #pragma unroll
    for (int s = 0; s < STEPS; ++s) {
        const float4 nxA = pxA[s & 1], nxB = pxB[s & 1];
        const float4 nyA = pyA[s & 1], nyB = pyB[s & 1];
        if (s + 2 < STEPS) {
            const int r = O + s + 2;
            float4 a = z4, b2 = z4, c = z4, d = z4;
            if (lok && r < H) {
                a  = *reinterpret_cast<const float4*>(xb + (size_t)r * W + cb);
                b2 = *reinterpret_cast<const float4*>(xb + (size_t)r * W + cb + 4);
                c  = *reinterpret_cast<const float4*>(yb + (size_t)r * W + cb);
                d  = *reinterpret_cast<const float4*>(yb + (size_t)r * W + cb + 4);
            }
            pxA[s & 1] = a; pxB[s & 1] = b2; pyA[s & 1] = c; pyB[s & 1] = d;
        }

        const int ph = s % 5;
        racc(csxA, nxA, hxA[ph]); racc(csxB, nxB, hxB[ph]);
        racc(csyA, nyA, hyA[ph]); racc(csyB, nyB, hyB[ph]);
        hxA[ph] = nxA; hxB[ph] = nxB; hyA[ph] = nyA; hyB[ph] = nyB;

        if (s >= 4) {
            const int pc = (ph + 3) % 5;           // slot of center row r-2
            // neighbor lane's chunk-A colsums (cols cb+8..cb+11)
            float nbx0 = __shfl_down(csxA.x, 1), nbx1 = __shfl_down(csxA.y, 1);
            float nbx2 = __shfl_down(csxA.z, 1), nbx3 = __shfl_down(csxA.w, 1);
            float nby0 = __shfl_down(csyA.x, 1), nby1 = __shfl_down(csyA.y, 1);
            float nby2 = __shfl_down(csyA.z, 1), nby3 = __shfl_down(csyA.w, 1);
            // neighbor lane's chunk-A centers (cols cb+8, cb+9) of row r-2
            float cnx0 = __shfl_down(hxA[pc].x, 1), cnx1 = __shfl_down(hxA[pc].y, 1);
            float cny0 = __shfl_down(hyA[pc].x, 1), cny1 = __shfl_down(hyA[pc].y, 1);

            // rolling horizontal 5-sums of colsums: 8 windows (cb..cb+7)
            float sxA0 = csxA.x + csxA.y + csxA.z + csxA.w + csxB.x;
            float sxA1 = sxA0 - csxA.x + csxB.y;
            float sxA2 = sxA1 - csxA.y + csxB.z;
            float sxA3 = sxA2 - csxA.z + csxB.w;
            float sxB0 = sxA3 - csxA.w + nbx0;
            float sxB1 = sxB0 - csxB.x + nbx1;
            float sxB2 = sxB1 - csxB.y + nbx2;
            float sxB3 = sxB2 - csxB.z + nbx3;
            float syA0 = csyA.x + csyA.y + csyA.z + csyA.w + csyB.x;
            float syA1 = syA0 - csyA.x + csyB.y;
            float syA2 = syA1 - csyA.y + csyB.z;
            float syA3 = syA2 - csyA.z + csyB.w;
            float syB0 = syA3 - csyA.w + nby0;
            float syB1 = syB0 - csyB.x + nby1;
            float syB2 = syB1 - csyB.y + nby2;
            float syB3 = syB2 - csyB.z + nby3;

            // deviation products at cols cb..cb+7 (centers row r-2, col+2)
            float4 pA, pB;
            pA.x = (hxA[pc].z - sxA0 * k) * (hyA[pc].z - syA0 * k);
            pA.y = (hxA[pc].w - sxA1 * k) * (hyA[pc].w - syA1 * k);
            pA.z = (hxB[pc].x - sxA2 * k) * (hyB[pc].x - syA2 * k);
            pA.w = (hxB[pc].y - sxA3 * k) * (hyB[pc].y - syA3 * k);
            pB.x = (hxB[pc].z - sxB0 * k) * (hyB[pc].z - syB0 * k);
            pB.y = (hxB[pc].w - sxB1 * k) * (hyB[pc].w - syB1 * k);
            pB.z = (cnx0      - sxB2 * k) * (cny0      - syB2 * k);
            pB.w = (cnx1      - sxB3 * k) * (cny1      - syB3 * k);

            const int pp = (s + 1) % 5;
            racc(psA, pA, hpA[pp]); racc(psB, pB, hpB[pp]);
            hpA[pp] = pA; hpB[pp] = pB;

            if (s >= 8) {
                float np0 = __shfl_down(psA.x, 1), np1 = __shfl_down(psA.y, 1);
                float np2 = __shfl_down(psA.z, 1), np3 = __shfl_down(psA.w, 1);
                float oA0 = psA.x + psA.y + psA.z + psA.w + psB.x;
                float oA1 = oA0 - psA.x + psB.y;
                float oA2 = oA1 - psA.y + psB.z;
                float oA3 = oA2 - psA.z + psB.w;
                float oB0 = oA3 - psA.w + np0;
                float oB1 = oB0 - psB.x + np1;
                float oB2 = oB1 - psB.y + np2;
                float oB3 = oB2 - psB.z + np3;
                const int o = O + s - 8;
                if (sok && o < OH) {
                    vfloat4 v0 = { oA0 * k, oA1 * k, oA2 * k, oA3 * k };
                    vfloat4 v1 = { oB0 * k, oB1 * k, oB2 * k, oB3 * k };
                    float* p = ob + (size_t)o * OW + cb;
                    __builtin_nontemporal_store(v0, reinterpret_cast<vfloat4*>(p));
                    __builtin_nontemporal_store(v1, reinterpret_cast<vfloat4*>(p + 4));
                }
            }
        }
    }
}

extern "C" void kernel_launch(void* const* d_in, const int* in_sizes, int n_in,
                              void* d_out, int out_size, void* d_ws, size_t ws_size,
                              hipStream_t stream) {
    const float* x = (const float*)d_in[0];
    const float* y = (const float*)d_in[1];
    float* out = (float*)d_out;

    dim3 grid(NGRP, NBANDS / WPB, NB);   // 3 x 16 x 16 = 768 blocks x 4 waves
    dim3 block(WPB * 64);
    cov_kernel<<<grid, block, 0, stream>>>(x, y, out);
}

// Round 12
// 53.921 us; speedup vs baseline: 1.0453x; 1.0453x over previous
//
#include <hip/hip_runtime.h>

#define H 1024
#define W 1024
#define OH 1016
#define OW 1016
#define NB 16
#define BAND 16            // output rows per task
#define STEPS (BAND + 8)   // input rows swept per task
#define WCOLS 248          // useful output cols per 64-lane wave
#define NWX 5              // ceil(1016 / 248)
#define NBANDS 64
#define WPB 4              // waves per block (256 threads)
#define NWG 640            // persistent: 2.5 WG/CU, 2 tasks per wave
#define TOTAL_TASKS (NWX * NBANDS * NB)   // 5120
#define TOTAL_WAVES (NWG * WPB)           // 2560

typedef float vfloat4 __attribute__((ext_vector_type(4)));

__global__ __launch_bounds__(256)
void cov_kernel(const float* __restrict__ xg,
                const float* __restrict__ yg,
                float* __restrict__ outg) {
    const int t  = threadIdx.x & 63;               // lane 0..63
    const int wv = threadIdx.x >> 6;               // wave in block
    const int g  = blockIdx.x * WPB + wv;          // global wave id

    const float4 z4 = make_float4(0.f, 0.f, 0.f, 0.f);
    const float k = 1.0f / 25.0f;
    const bool lok0 = true;                        // refined per task below

    for (int task = g; task < TOTAL_TASKS; task += TOTAL_WAVES) {
        // decode: img-major, then column group, then band (adjacent bands
        // consecutive across waves for L2 locality)
        const int img  = task / (NWX * NBANDS);
        const int rem  = task - img * (NWX * NBANDS);
        const int wx   = rem >> 6;                 // 0..4
        const int band = rem & 63;                 // 0..63

        const int cb = wx * WCOLS + 4 * t;
        const int O  = band * BAND;
        const bool lok = (cb <= W - 4);
        const bool sok = (t <= 61) && (cb <= OW - 4);

        const float* xb = xg + (size_t)img * H * W;
        const float* yb = yg + (size_t)img * H * W;
        float* ob = outg + (size_t)img * OH * OW;

        float4 hx[5], hy[5], hp[5];
        #pragma unroll
        for (int i = 0; i < 5; ++i) { hx[i] = z4; hy[i] = z4; hp[i] = z4; }
        float4 csx = z4, csy = z4, ps = z4;

        float4 pnx[2], pny[2];
        #pragma unroll
        for (int i = 0; i < 2; ++i) {
            const int r = O + i;
            float4 vx = z4, vy = z4;
            if (lok && r < H) {
                vx = *reinterpret_cast<const float4*>(xb + (size_t)r * W + cb);
                vy = *reinterpret_cast<const float4*>(yb + (size_t)r * W + cb);
            }
            pnx[i] = vx; pny[i] = vy;
        }

        #pragma unroll
        for (int s = 0; s < STEPS; ++s) {
            const float4 nx = pnx[s & 1];
            const float4 ny = pny[s & 1];
            if (s + 2 < STEPS) {
                const int r = O + s + 2;
                float4 vx = z4, vy = z4;
                if (lok && r < H) {
                    vx = *reinterpret_cast<const float4*>(xb + (size_t)r * W + cb);
                    vy = *reinterpret_cast<const float4*>(yb + (size_t)r * W + cb);
                }
                pnx[s & 1] = vx; pny[s & 1] = vy;
            }

            const int ph = s % 5;
            csx.x += nx.x - hx[ph].x; csx.y += nx.y - hx[ph].y;
            csx.z += nx.z - hx[ph].z; csx.w += nx.w - hx[ph].w;
            csy.x += ny.x - hy[ph].x; csy.y += ny.y - hy[ph].y;
            csy.z += ny.z - hy[ph].z; csy.w += ny.w - hy[ph].w;
            hx[ph] = nx; hy[ph] = ny;

            if (s >= 4) {
                const int pc = (ph + 3) % 5;        // slot of center row r-2
                float bx0 = __shfl_down(csx.x, 1), bx1 = __shfl_down(csx.y, 1);
                float bx2 = __shfl_down(csx.z, 1), bx3 = __shfl_down(csx.w, 1);
                float by0 = __shfl_down(csy.x, 1), by1 = __shfl_down(csy.y, 1);
                float by2 = __shfl_down(csy.z, 1), by3 = __shfl_down(csy.w, 1);
                float cx2 = __shfl_down(hx[pc].x, 1), cx3 = __shfl_down(hx[pc].y, 1);
                float cy2 = __shfl_down(hy[pc].x, 1), cy3 = __shfl_down(hy[pc].y, 1);

                float sx0 = csx.x + csx.y + csx.z + csx.w + bx0;
                float sx1 = sx0 - csx.x + bx1;
                float sx2 = sx1 - csx.y + bx2;
                float sx3 = sx2 - csx.z + bx3;
                float sy0 = csy.x + csy.y + csy.z + csy.w + by0;
                float sy1 = sy0 - csy.x + by1;
                float sy2 = sy1 - csy.y + by2;
                float sy3 = sy2 - csy.z + by3;

                float4 p;
                p.x = (hx[pc].z - sx0 * k) * (hy[pc].z - sy0 * k);
                p.y = (hx[pc].w - sx1 * k) * (hy[pc].w - sy1 * k);
                p.z = (cx2      - sx2 * k) * (cy2      - sy2 * k);
                p.w = (cx3      - sx3 * k) * (cy3      - sy3 * k);

                const int pp = (s + 1) % 5;
                ps.x += p.x - hp[pp].x; ps.y += p.y - hp[pp].y;
                ps.z += p.z - hp[pp].z; ps.w += p.w - hp[pp].w;
                hp[pp] = p;

                if (s >= 8) {
                    float bp0 = __shfl_down(ps.x, 1), bp1 = __shfl_down(ps.y, 1);
                    float bp2 = __shfl_down(ps.z, 1), bp3 = __shfl_down(ps.w, 1);
                    float s0 = ps.x + ps.y + ps.z + ps.w + bp0;
                    float s1 = s0 - ps.x + bp1;
                    float s2 = s1 - ps.y + bp2;
                    float s3 = s2 - ps.z + bp3;
                    const int o = O + s - 8;
                    if (sok && o < OH) {
                        vfloat4 ov = { s0 * k, s1 * k, s2 * k, s3 * k };
                        __builtin_nontemporal_store(ov,
                            reinterpret_cast<vfloat4*>(ob + (size_t)o * OW + cb));
                    }
                }
            }
        }
    }
    (void)lok0;
}

extern "C" void kernel_launch(void* const* d_in, const int* in_sizes, int n_in,
                              void* d_out, int out_size, void* d_ws, size_t ws_size,
                              hipStream_t stream) {
    const float* x = (const float*)d_in[0];
    const float* y = (const float*)d_in[1];
    float* out = (float*)d_out;

    dim3 grid(NWG);                 // 640 persistent workgroups x 4 waves
    dim3 block(WPB * 64);
    cov_kernel<<<grid, block, 0, stream>>>(x, y, out);
}

// Round 14
// 43.811 us; speedup vs baseline: 1.2866x; 1.2308x over previous
//
#include <hip/hip_runtime.h>

#define H 1024
#define W 1024
#define OH 1016
#define OW 1016
#define NB 16
#define BAND 64            // output rows per wave; 16*64 = 1024 exact
#define STEPS (BAND + 8)   // 72 input rows swept per wave
#define WCOLS 248          // useful output cols per 64-lane wave
#define NWX 5              // ceil(1016 / 248)
#define NBANDS 16
#define WPB 4              // waves per block (256 threads)

typedef float vfloat4 __attribute__((ext_vector_type(4)));

__global__ __launch_bounds__(256)
void cov_kernel(const float* __restrict__ xg,
                const float* __restrict__ yg,
                float* __restrict__ outg) {
    const int t    = threadIdx.x & 63;             // lane 0..63
    const int wv   = threadIdx.x >> 6;             // wave in block
    const int wx   = blockIdx.x;                   // column group
    const int band = blockIdx.y * WPB + wv;        // row band 0..15
    const int img  = blockIdx.z;

    const int cb = wx * WCOLS + 4 * t;             // lane's first column
    const int O  = band * BAND;                    // first output row of band
    const bool lok = (cb <= W - 4);
    const bool sok = (t <= 61) && (cb <= OW - 4);

    const float* xb = xg + (size_t)img * H * W;
    const float* yb = yg + (size_t)img * H * W;
    float* ob = outg + (size_t)img * OH * OW;

    const float4 z4 = make_float4(0.f, 0.f, 0.f, 0.f);
    float4 hx[5], hy[5], hp[5];
    #pragma unroll
    for (int i = 0; i < 5; ++i) { hx[i] = z4; hy[i] = z4; hp[i] = z4; }
    float4 csx = z4, csy = z4, ps = z4;
    const float k = 1.0f / 25.0f;

    float4 pnx[2], pny[2];

    // helper expressions as macros so all indices stay literal after unroll
#define LOAD_ROW(R, VX, VY)                                                    \
    {                                                                          \
        float4 _vx = z4, _vy = z4;                                             \
        if (lok && (R) < H) {                                                  \
            _vx = *reinterpret_cast<const float4*>(xb + (size_t)(R) * W + cb); \
            _vy = *reinterpret_cast<const float4*>(yb + (size_t)(R) * W + cb); \
        }                                                                      \
        VX = _vx; VY = _vy;                                                    \
    }

#define PUSH_ROW(NX, NY, PH)                                                   \
    {                                                                          \
        csx.x += (NX).x - hx[PH].x; csx.y += (NX).y - hx[PH].y;                \
        csx.z += (NX).z - hx[PH].z; csx.w += (NX).w - hx[PH].w;                \
        csy.x += (NY).x - hy[PH].x; csy.y += (NY).y - hy[PH].y;                \
        csy.z += (NY).z - hy[PH].z; csy.w += (NY).w - hy[PH].w;                \
        hx[PH] = (NX); hy[PH] = (NY);                                          \
    }

#define PROD_ROW(PC, PP)                                                       \
    {                                                                          \
        float bx0 = __shfl_down(csx.x, 1), bx1 = __shfl_down(csx.y, 1);        \
        float bx2 = __shfl_down(csx.z, 1), bx3 = __shfl_down(csx.w, 1);        \
        float by0 = __shfl_down(csy.x, 1), by1 = __shfl_down(csy.y, 1);        \
        float by2 = __shfl_down(csy.z, 1), by3 = __shfl_down(csy.w, 1);        \
        float cx2 = __shfl_down(hx[PC].x, 1), cx3 = __shfl_down(hx[PC].y, 1);  \
        float cy2 = __shfl_down(hy[PC].x, 1), cy3 = __shfl_down(hy[PC].y, 1);  \
        float sx0 = csx.x + csx.y + csx.z + csx.w + bx0;                       \
        float sx1 = sx0 - csx.x + bx1;                                         \
        float sx2 = sx1 - csx.y + bx2;                                         \
        float sx3 = sx2 - csx.z + bx3;                                         \
        float sy0 = csy.x + csy.y + csy.z + csy.w + by0;                       \
        float sy1 = sy0 - csy.x + by1;                                         \
        float sy2 = sy1 - csy.y + by2;                                         \
        float sy3 = sy2 - csy.z + by3;                                         \
        float4 p;                                                              \
        p.x = (hx[PC].z - sx0 * k) * (hy[PC].z - sy0 * k);                     \
        p.y = (hx[PC].w - sx1 * k) * (hy[PC].w - sy1 * k);                     \
        p.z = (cx2       - sx2 * k) * (cy2       - sy2 * k);                   \
        p.w = (cx3       - sx3 * k) * (cy3       - sy3 * k);                   \
        ps.x += p.x - hp[PP].x; ps.y += p.y - hp[PP].y;                        \
        ps.z += p.z - hp[PP].z; ps.w += p.w - hp[PP].w;                        \
        hp[PP] = p;                                                            \
    }

#define OUT_ROW(O_ROW)                                                         \
    {                                                                          \
        float bp0 = __shfl_down(ps.x, 1), bp1 = __shfl_down(ps.y, 1);          \
        float bp2 = __shfl_down(ps.z, 1), bp3 = __shfl_down(ps.w, 1);          \
        float s0 = ps.x + ps.y + ps.z + ps.w + bp0;                            \
        float s1 = s0 - ps.x + bp1;                                            \
        float s2 = s1 - ps.y + bp2;                                            \
        float s3 = s2 - ps.z + bp3;                                            \
        if (sok && (O_ROW) < OH) {                                             \
            vfloat4 ov = { s0 * k, s1 * k, s2 * k, s3 * k };                   \
            __builtin_nontemporal_store(ov,                                    \
                reinterpret_cast<vfloat4*>(ob + (size_t)(O_ROW) * OW + cb));   \
        }                                                                      \
    }

    // ---- prime prefetch: rows O, O+1 ----
    LOAD_ROW(O + 0, pnx[0], pny[0]);
    LOAD_ROW(O + 1, pnx[1], pny[1]);

    // ---- prologue: s = 0..7 (no outputs) ----
    #pragma unroll
    for (int j = 0; j < 8; ++j) {
        const float4 nx = pnx[j % 2], ny = pny[j % 2];
        LOAD_ROW(O + j + 2, pnx[j % 2], pny[j % 2]);
        PUSH_ROW(nx, ny, j % 5);
        if (j >= 4) PROD_ROW(((j % 5) + 3) % 5, (j + 1) % 5);
    }

    // ---- main: s = 8..67, rolled with unroll-10 (ss ≡ 8 mod 10) ----
    for (int ss = 8; ss < 68; ss += 10) {
        #pragma unroll
        for (int j = 0; j < 10; ++j) {
            // actual s = ss + j; ss ≡ 8 (mod 10) so s%5 = (8+j)%5, s%2 = j%2
            const int ph = (8 + j) % 5;
            const int pc = (ph + 3) % 5;
            const int pp = (8 + j + 1) % 5;
            const int pf = j % 2;
            const int s  = ss + j;
            const float4 nx = pnx[pf], ny = pny[pf];
            if (s + 2 < STEPS) LOAD_ROW(O + s + 2, pnx[pf], pny[pf]);
            PUSH_ROW(nx, ny, ph);
            PROD_ROW(pc, pp);
            OUT_ROW(O + s - 8);
        }
    }

    // ---- tail: s = 68..71 (FIX: keep prefetching rows 70, 71) ----
    #pragma unroll
    for (int j = 0; j < 4; ++j) {
        const int s  = 68 + j;                      // 68 ≡ 8 (mod 10)
        const int ph = (68 + j) % 5;
        const int pc = (ph + 3) % 5;
        const int pp = (68 + j + 1) % 5;
        const int pf = j % 2;                       // 68 even
        const float4 nx = pnx[pf], ny = pny[pf];
        if (s + 2 < STEPS) LOAD_ROW(O + s + 2, pnx[pf], pny[pf]);
        PUSH_ROW(nx, ny, ph);
        PROD_ROW(pc, pp);
        OUT_ROW(O + s - 8);
    }
}

extern "C" void kernel_launch(void* const* d_in, const int* in_sizes, int n_in,
                              void* d_out, int out_size, void* d_ws, size_t ws_size,
                              hipStream_t stream) {
    const float* x = (const float*)d_in[0];
    const float* y = (const float*)d_in[1];
    float* out = (float*)d_out;

    dim3 grid(NWX, NBANDS / WPB, NB);   // 5 x 4 x 16 = 320 blocks x 4 waves = 1280 waves
    dim3 block(WPB * 64);
    cov_kernel<<<grid, block, 0, stream>>>(x, y, out);
}

// Round 15
// 42.696 us; speedup vs baseline: 1.3202x; 1.0261x over previous
//
#include <hip/hip_runtime.h>

#define H 1024
#define W 1024
#define OH 1016
#define OW 1016
#define NB 16
#define BAND 64            // output rows per wave; 16*64 = 1024 exact
#define STEPS (BAND + 8)   // 72 input rows swept per wave
#define WCOLS 248          // useful output cols per 64-lane wave
#define NWX 5              // ceil(1016 / 248)
#define NBANDS 16

typedef float vfloat4 __attribute__((ext_vector_type(4)));

__global__ __launch_bounds__(64)
void cov_kernel(const float* __restrict__ xg,
                const float* __restrict__ yg,
                float* __restrict__ outg) {
    const int t    = threadIdx.x;                  // lane 0..63
    const int wx   = blockIdx.x;                   // column group
    const int band = blockIdx.y;                   // row band 0..15
    const int img  = blockIdx.z;

    const int cb = wx * WCOLS + 4 * t;             // lane's first column
    const int O  = band * BAND;                    // first output row of band
    const bool lok = (cb <= W - 4);
    const bool sok = (t <= 61) && (cb <= OW - 4);

    const float* xb = xg + (size_t)img * H * W;
    const float* yb = yg + (size_t)img * H * W;
    float* ob = outg + (size_t)img * OH * OW;

    const float4 z4 = make_float4(0.f, 0.f, 0.f, 0.f);
    float4 hx[5], hy[5], hp[5];
    #pragma unroll
    for (int i = 0; i < 5; ++i) { hx[i] = z4; hy[i] = z4; hp[i] = z4; }
    float4 csx = z4, csy = z4, ps = z4;
    const float k = 1.0f / 25.0f;

    float4 pnx[2], pny[2];

    // helper expressions as macros so all indices stay literal after unroll
#define LOAD_ROW(R, VX, VY)                                                    \
    {                                                                          \
        float4 _vx = z4, _vy = z4;                                             \
        if (lok && (R) < H) {                                                  \
            _vx = *reinterpret_cast<const float4*>(xb + (size_t)(R) * W + cb); \
            _vy = *reinterpret_cast<const float4*>(yb + (size_t)(R) * W + cb); \
        }                                                                      \
        VX = _vx; VY = _vy;                                                    \
    }

#define PUSH_ROW(NX, NY, PH)                                                   \
    {                                                                          \
        csx.x += (NX).x - hx[PH].x; csx.y += (NX).y - hx[PH].y;                \
        csx.z += (NX).z - hx[PH].z; csx.w += (NX).w - hx[PH].w;                \
        csy.x += (NY).x - hy[PH].x; csy.y += (NY).y - hy[PH].y;                \
        csy.z += (NY).z - hy[PH].z; csy.w += (NY).w - hy[PH].w;                \
        hx[PH] = (NX); hy[PH] = (NY);                                          \
    }

#define PROD_ROW(PC, PP)                                                       \
    {                                                                          \
        float bx0 = __shfl_down(csx.x, 1), bx1 = __shfl_down(csx.y, 1);        \
        float bx2 = __shfl_down(csx.z, 1), bx3 = __shfl_down(csx.w, 1);        \
        float by0 = __shfl_down(csy.x, 1), by1 = __shfl_down(csy.y, 1);        \
        float by2 = __shfl_down(csy.z, 1), by3 = __shfl_down(csy.w, 1);        \
        float cx2 = __shfl_down(hx[PC].x, 1), cx3 = __shfl_down(hx[PC].y, 1);  \
        float cy2 = __shfl_down(hy[PC].x, 1), cy3 = __shfl_down(hy[PC].y, 1);  \
        float sx0 = csx.x + csx.y + csx.z + csx.w + bx0;                       \
        float sx1 = sx0 - csx.x + bx1;                                         \
        float sx2 = sx1 - csx.y + bx2;                                         \
        float sx3 = sx2 - csx.z + bx3;                                         \
        float sy0 = csy.x + csy.y + csy.z + csy.w + by0;                       \
        float sy1 = sy0 - csy.x + by1;                                         \
        float sy2 = sy1 - csy.y + by2;                                         \
        float sy3 = sy2 - csy.z + by3;                                         \
        float4 p;                                                              \
        p.x = (hx[PC].z - sx0 * k) * (hy[PC].z - sy0 * k);                     \
        p.y = (hx[PC].w - sx1 * k) * (hy[PC].w - sy1 * k);                     \
        p.z = (cx2       - sx2 * k) * (cy2       - sy2 * k);                   \
        p.w = (cx3       - sx3 * k) * (cy3       - sy3 * k);                   \
        ps.x += p.x - hp[PP].x; ps.y += p.y - hp[PP].y;                        \
        ps.z += p.z - hp[PP].z; ps.w += p.w - hp[PP].w;                        \
        hp[PP] = p;                                                            \
    }

#define OUT_ROW(O_ROW)                                                         \
    {                                                                          \
        float bp0 = __shfl_down(ps.x, 1), bp1 = __shfl_down(ps.y, 1);          \
        float bp2 = __shfl_down(ps.z, 1), bp3 = __shfl_down(ps.w, 1);          \
        float s0 = ps.x + ps.y + ps.z + ps.w + bp0;                            \
        float s1 = s0 - ps.x + bp1;                                            \
        float s2 = s1 - ps.y + bp2;                                            \
        float s3 = s2 - ps.z + bp3;                                            \
        if (sok && (O_ROW) < OH) {                                             \
            vfloat4 ov = { s0 * k, s1 * k, s2 * k, s3 * k };                   \
            __builtin_nontemporal_store(ov,                                    \
                reinterpret_cast<vfloat4*>(ob + (size_t)(O_ROW) * OW + cb));   \
        }                                                                      \
    }

    // ---- prime prefetch: rows O, O+1 ----
    LOAD_ROW(O + 0, pnx[0], pny[0]);
    LOAD_ROW(O + 1, pnx[1], pny[1]);

    // ---- prologue: s = 0..7 (no outputs) ----
    #pragma unroll
    for (int j = 0; j < 8; ++j) {
        const float4 nx = pnx[j % 2], ny = pny[j % 2];
        LOAD_ROW(O + j + 2, pnx[j % 2], pny[j % 2]);
        PUSH_ROW(nx, ny, j % 5);
        if (j >= 4) PROD_ROW(((j % 5) + 3) % 5, (j + 1) % 5);
    }

    // ---- main: s = 8..67, rolled with unroll-10 (ss ≡ 8 mod 10) ----
    for (int ss = 8; ss < 68; ss += 10) {
        #pragma unroll
        for (int j = 0; j < 10; ++j) {
            // actual s = ss + j; ss ≡ 8 (mod 10) so s%5 = (8+j)%5, s%2 = j%2
            const int ph = (8 + j) % 5;
            const int pc = (ph + 3) % 5;
            const int pp = (8 + j + 1) % 5;
            const int pf = j % 2;
            const int s  = ss + j;
            const float4 nx = pnx[pf], ny = pny[pf];
            if (s + 2 < STEPS) LOAD_ROW(O + s + 2, pnx[pf], pny[pf]);
            PUSH_ROW(nx, ny, ph);
            PROD_ROW(pc, pp);
            OUT_ROW(O + s - 8);
        }
    }

    // ---- tail: s = 68..71 (keeps prefetching rows 70, 71) ----
    #pragma unroll
    for (int j = 0; j < 4; ++j) {
        const int s  = 68 + j;                      // 68 ≡ 8 (mod 10)
        const int ph = (68 + j) % 5;
        const int pc = (ph + 3) % 5;
        const int pp = (68 + j + 1) % 5;
        const int pf = j % 2;                       // 68 even
        const float4 nx = pnx[pf], ny = pny[pf];
        if (s + 2 < STEPS) LOAD_ROW(O + s + 2, pnx[pf], pny[pf]);
        PUSH_ROW(nx, ny, ph);
        PROD_ROW(pc, pp);
        OUT_ROW(O + s - 8);
    }
}

extern "C" void kernel_launch(void* const* d_in, const int* in_sizes, int n_in,
                              void* d_out, int out_size, void* d_ws, size_t ws_size,
                              hipStream_t stream) {
    const float* x = (const float*)d_in[0];
    const float* y = (const float*)d_in[1];
    float* out = (float*)d_out;

    dim3 grid(NWX, NBANDS, NB);     // 5 x 16 x 16 = 1280 one-wave blocks = 5/CU exact
    dim3 block(64);
    cov_kernel<<<grid, block, 0, stream>>>(x, y, out);
}

// Round 16
// 41.108 us; speedup vs baseline: 1.3712x; 1.0386x over previous
//
#include <hip/hip_runtime.h>

#define H 1024
#define W 1024
#define OH 1016
#define OW 1016
#define NB 16
#define BAND 64            // output rows per wave; 16*64 = 1024 exact
#define STEPS (BAND + 8)   // 72 input rows swept per wave
#define WCOLS 248          // useful output cols per 64-lane wave
#define NWX 5              // ceil(1016 / 248)
#define NBANDS 16
#define PFD 4              // prefetch depth (row-pairs in flight)

typedef float vfloat4 __attribute__((ext_vector_type(4)));

__global__ __launch_bounds__(64)
void cov_kernel(const float* __restrict__ xg,
                const float* __restrict__ yg,
                float* __restrict__ outg) {
    const int t    = threadIdx.x;                  // lane 0..63
    const int wx   = blockIdx.x;                   // column group
    const int band = blockIdx.y;                   // row band 0..15
    const int img  = blockIdx.z;

    const int cb = wx * WCOLS + 4 * t;             // lane's first column
    const int O  = band * BAND;                    // first output row of band
    const bool lok = (cb <= W - 4);
    const bool sok = (t <= 61) && (cb <= OW - 4);

    const float* xb = xg + (size_t)img * H * W;
    const float* yb = yg + (size_t)img * H * W;
    float* ob = outg + (size_t)img * OH * OW;

    const float4 z4 = make_float4(0.f, 0.f, 0.f, 0.f);
    float4 hx[5], hy[5], hp[5];
    #pragma unroll
    for (int i = 0; i < 5; ++i) { hx[i] = z4; hy[i] = z4; hp[i] = z4; }
    float4 csx = z4, csy = z4, ps = z4;
    const float k = 1.0f / 25.0f;

    float4 pnx[PFD], pny[PFD];

#define LOAD_ROW(R, VX, VY)                                                    \
    {                                                                          \
        float4 _vx = z4, _vy = z4;                                             \
        if (lok && (R) < H) {                                                  \
            _vx = *reinterpret_cast<const float4*>(xb + (size_t)(R) * W + cb); \
            _vy = *reinterpret_cast<const float4*>(yb + (size_t)(R) * W + cb); \
        }                                                                      \
        VX = _vx; VY = _vy;                                                    \
    }

#define PUSH_ROW(NX, NY, PH)                                                   \
    {                                                                          \
        csx.x += (NX).x - hx[PH].x; csx.y += (NX).y - hx[PH].y;                \
        csx.z += (NX).z - hx[PH].z; csx.w += (NX).w - hx[PH].w;                \
        csy.x += (NY).x - hy[PH].x; csy.y += (NY).y - hy[PH].y;                \
        csy.z += (NY).z - hy[PH].z; csy.w += (NY).w - hy[PH].w;                \
        hx[PH] = (NX); hy[PH] = (NY);                                          \
    }

#define PROD_ROW(PC, PP)                                                       \
    {                                                                          \
        float bx0 = __shfl_down(csx.x, 1), bx1 = __shfl_down(csx.y, 1);        \
        float bx2 = __shfl_down(csx.z, 1), bx3 = __shfl_down(csx.w, 1);        \
        float by0 = __shfl_down(csy.x, 1), by1 = __shfl_down(csy.y, 1);        \
        float by2 = __shfl_down(csy.z, 1), by3 = __shfl_down(csy.w, 1);        \
        float cx2 = __shfl_down(hx[PC].x, 1), cx3 = __shfl_down(hx[PC].y, 1);  \
        float cy2 = __shfl_down(hy[PC].x, 1), cy3 = __shfl_down(hy[PC].y, 1);  \
        float sx0 = csx.x + csx.y + csx.z + csx.w + bx0;                       \
        float sx1 = sx0 - csx.x + bx1;                                         \
        float sx2 = sx1 - csx.y + bx2;                                         \
        float sx3 = sx2 - csx.z + bx3;                                         \
        float sy0 = csy.x + csy.y + csy.z + csy.w + by0;                       \
        float sy1 = sy0 - csy.x + by1;                                         \
        float sy2 = sy1 - csy.y + by2;                                         \
        float sy3 = sy2 - csy.z + by3;                                         \
        float4 p;                                                              \
        p.x = (hx[PC].z - sx0 * k) * (hy[PC].z - sy0 * k);                     \
        p.y = (hx[PC].w - sx1 * k) * (hy[PC].w - sy1 * k);                     \
        p.z = (cx2       - sx2 * k) * (cy2       - sy2 * k);                   \
        p.w = (cx3       - sx3 * k) * (cy3       - sy3 * k);                   \
        ps.x += p.x - hp[PP].x; ps.y += p.y - hp[PP].y;                        \
        ps.z += p.z - hp[PP].z; ps.w += p.w - hp[PP].w;                        \
        hp[PP] = p;                                                            \
    }

#define OUT_ROW(O_ROW)                                                         \
    {                                                                          \
        float bp0 = __shfl_down(ps.x, 1), bp1 = __shfl_down(ps.y, 1);          \
        float bp2 = __shfl_down(ps.z, 1), bp3 = __shfl_down(ps.w, 1);          \
        float s0 = ps.x + ps.y + ps.z + ps.w + bp0;                            \
        float s1 = s0 - ps.x + bp1;                                            \
        float s2 = s1 - ps.y + bp2;                                            \
        float s3 = s2 - ps.z + bp3;                                            \
        if (sok && (O_ROW) < OH) {                                             \
            vfloat4 ov = { s0 * k, s1 * k, s2 * k, s3 * k };                   \
            __builtin_nontemporal_store(ov,                                    \
                reinterpret_cast<vfloat4*>(ob + (size_t)(O_ROW) * OW + cb));   \
        }                                                                      \
    }

    // ---- prime prefetch: rows O..O+3 into slots 0..3 ----
    LOAD_ROW(O + 0, pnx[0], pny[0]);
    LOAD_ROW(O + 1, pnx[1], pny[1]);
    LOAD_ROW(O + 2, pnx[2], pny[2]);
    LOAD_ROW(O + 3, pnx[3], pny[3]);

    // ---- prologue: s = 0..7 (no outputs) ----
    // consume row s from slot s%4; issue row s+4 into slot s%4
    #pragma unroll
    for (int j = 0; j < 8; ++j) {
        const int pf = j % 4;
        const float4 nx = pnx[pf], ny = pny[pf];
        LOAD_ROW(O + j + 4, pnx[pf], pny[pf]);     // j+4 <= 11 < STEPS
        PUSH_ROW(nx, ny, j % 5);
        if (j >= 4) PROD_ROW(((j % 5) + 3) % 5, (j + 1) % 5);
    }

    // ---- main: s = 8..67, rolled with unroll-20 (lcm(5,4); ss ≡ 8 mod 20) ----
    for (int ss = 8; ss < 68; ss += 20) {
        #pragma unroll
        for (int j = 0; j < 20; ++j) {
            // actual s = ss + j; ss ≡ 8 (mod 20): s%5 = (8+j)%5, s%4 = j%4
            const int ph = (8 + j) % 5;
            const int pc = (ph + 3) % 5;
            const int pp = (8 + j + 1) % 5;
            const int pf = j % 4;                  // 8%4 == 0
            const int s  = ss + j;                 // max 67 -> loads row 71 max
            const float4 nx = pnx[pf], ny = pny[pf];
            LOAD_ROW(O + s + 4, pnx[pf], pny[pf]); // s+4 <= 71 < STEPS always
            PUSH_ROW(nx, ny, ph);
            PROD_ROW(pc, pp);
            OUT_ROW(O + s - 8);
        }
    }

    // ---- tail: s = 68..71 (rows 68..71 already in flight; no more loads) ----
    #pragma unroll
    for (int j = 0; j < 4; ++j) {
        const int s  = 68 + j;
        const int ph = (68 + j) % 5;               // = (3+j)%5
        const int pc = (ph + 3) % 5;
        const int pp = (68 + j + 1) % 5;
        const int pf = j % 4;                      // 68%4 == 0
        const float4 nx = pnx[pf], ny = pny[pf];
        PUSH_ROW(nx, ny, ph);
        PROD_ROW(pc, pp);
        OUT_ROW(O + s - 8);
    }
}

extern "C" void kernel_launch(void* const* d_in, const int* in_sizes, int n_in,
                              void* d_out, int out_size, void* d_ws, size_t ws_size,
                              hipStream_t stream) {
    const float* x = (const float*)d_in[0];
    const float* y = (const float*)d_in[1];
    float* out = (float*)d_out;

    dim3 grid(NWX, NBANDS, NB);     // 5 x 16 x 16 = 1280 one-wave blocks = 5/CU exact
    dim3 block(64);
    cov_kernel<<<grid, block, 0, stream>>>(x, y, out);
}